// Round 14
// baseline (37602.307 us; speedup 1.0000x reference)
//
#include <hip/hip_runtime.h>
#include <stdint.h>
#include <math.h>

#define TSTEPS 256
#define BATCH  256
#define OBS_D  512
#define FEATD  512
#define NACT   15
#define HDIM   528
#define HB     (HDIM*BATCH)   /* 135168 */

/* ---- compact ws layout (same as R7, ~5.8 MB), plain [k][B] acts ---- */
#define OFF_ND    0
#define OFF_FLAG  65536
#define ALW_BYTES 262208
#define SB        91952
#define FXT       (SB)
#define FH0       (FXT + 4*HB)
#define FH1       (FH0 + 2*HB)
#define FC0       (FH1 + 2*HB)
#define FC1       (FC0 + HB)

/* ALW float offsets */
#define DBS0   0
#define DBS1   2112
#define DBENC  4224
#define DHW    4736
#define DHB    13184
#define DALW_N 13200

/* out float offsets */
#define OUT_POL   0
#define OUT_BASE  983040
#define OUT_ACT   1048576
#define OUT_H     1114112
#define OUT_C     1384448

__device__ __forceinline__ float sigf_(float x){ return 1.0f/(1.0f+expf(-x)); }

__device__ __forceinline__ uint32_t rotl32_(uint32_t x, uint32_t d){
  return (x<<d)|(x>>(32u-d));
}

/* JAX partitionable threefry 32-bit: bits = out0 ^ out1. [VERIFIED R5-R12] */
__device__ double gumbel_for(uint32_t idx){
  uint32_t x0 = 0u, x1 = idx;
  const uint32_t k0 = 0u, k1 = 1u;
  const uint32_t ks[3] = {k0, k1, 0x1BD11BDAu ^ k0 ^ k1};
  x0 += ks[0]; x1 += ks[1];
  const uint32_t R0[4] = {13u,15u,26u,6u}, R1[4] = {17u,29u,16u,24u};
  #pragma unroll
  for (int g=0; g<5; ++g){
    const uint32_t* r = (g&1) ? R1 : R0;
    #pragma unroll
    for (int j=0;j<4;++j){ x0 += x1; x1 = rotl32_(x1, r[j]); x1 ^= x0; }
    x0 += ks[(g+1)%3];
    x1 += ks[(g+2)%3] + (uint32_t)(g+1);
  }
  const uint32_t bits = x0 ^ x1;
  float u = __uint_as_float((bits>>9) | 0x3f800000u) - 1.0f;
  const float TINY = 1.17549435e-38f;
  u = u * (1.0f - TINY) + TINY;
  u = fmaxf(TINY, u);
  return -log(-log((double)u));
}

__global__ void zero_kernel(float* __restrict__ p, int n){
  int i = blockIdx.x*256 + threadIdx.x;
  if (i < n) p[i] = 0.0f;
}

__global__ void detect_term_kernel(const void* __restrict__ term, int* __restrict__ flag){
  __shared__ int s_nf, s_nb, s_ni;
  if (threadIdx.x==0){ s_nf=0; s_nb=0; s_ni=0; }
  __syncthreads();
  const uint8_t*  pb = (const uint8_t*)term;
  const uint32_t* pw = (const uint32_t*)term;
  int nf=0, nb=0, ni=0;
  for (int i=threadIdx.x; i<16384; i+=256){
    uint32_t v = pw[i];
    if (v == 0x3F800000u) nf++;
    if (v == 1u) ni++;
  }
  for (int o=threadIdx.x; o<65536; o+=256){
    if ((o&3) && pb[o]) nb++;
  }
  if (nf) atomicAdd(&s_nf, nf);
  if (nb) atomicAdd(&s_nb, nb);
  if (ni) atomicAdd(&s_ni, ni);
  __syncthreads();
  if (threadIdx.x==0){
    flag[0] = (s_nf>0) ? 2 : ((s_nb>0) ? 0 : ((s_ni>0) ? 1 : 0));
  }
}

__global__ void nd_kernel(const void* __restrict__ term, const int* __restrict__ flag,
                          float* __restrict__ nd){
  int i = blockIdx.x*256 + threadIdx.x;
  if (i >= TSTEPS*BATCH) return;
  int f = flag[0];
  bool done;
  if (f == 0)      done = ((const uint8_t*)term)[i] != 0;
  else if (f == 1) done = ((const int*)term)[i] != 0;
  else             done = ((const float*)term)[i] != 0.0f;
  nd[i] = done ? 0.0f : 1.0f;
}

__global__ void prep_small_kernel(float* __restrict__ alw,
    const float* __restrict__ bih0, const float* __restrict__ bhh0,
    const float* __restrict__ bih1, const float* __restrict__ bhh1,
    const float* __restrict__ benc,
    const float* __restrict__ Wpol, const float* __restrict__ bpol,
    const float* __restrict__ Wbase, const float* __restrict__ bbase){
  int i = blockIdx.x*256 + threadIdx.x;
  if (i >= DALW_N) return;
  if (i < 2112)            alw[DBS0 + i] = bih0[i] + bhh0[i];
  else if (i < 4224)       { int j=i-2112; alw[DBS1 + j] = bih1[j] + bhh1[j]; }
  else if (i < 4736)       { int j=i-4224; alw[DBENC + j] = benc[j]; }
  else if (i < 13184)      { int j=i-4736; int r=j/HDIM, k=j%HDIM;
                             alw[DHW + j] = (r<NACT ? Wpol[r*HDIM+k] : Wbase[k]); }
  else                     { int j=i-13184; alw[DHB + j] = (j<NACT ? bpol[j] : bbase[0]); }
}

/* LSTM tile: thread = (4 batch) x (2 j x 4 gates = 8 cols). Each weight load
   feeds 32 FMAs (batch-blocked) -> FMA-issue-bound either way the compiler
   schedules weight loads. Wave-uniform weight addresses (jl = tid>>6).
   Per-(col,b) FMA order identical to R7: bias -> x k-asc -> masked h k-asc. */
__device__ __forceinline__ void lstm_tile4(
    int tile, int jl, int step,
    const float* __restrict__ srcA, const float* __restrict__ srcB,
    const float* __restrict__ wih, const float* __restrict__ whh,
    const float* __restrict__ bsum,
    const float* __restrict__ nd, float* __restrict__ cbuf, float* __restrict__ hout,
    int b0)
{
  const int j0 = tile*8 + jl*2;
  float ndv[4];
  {
    const float4 n4 = *(const float4*)(nd + step*BATCH + b0);
    ndv[0]=n4.x; ndv[1]=n4.y; ndv[2]=n4.z; ndv[3]=n4.w;
  }
  float acc[8][4];
  const float* wA[8]; const float* wB[8];
  #pragma unroll
  for (int c=0;c<8;++c){
    const int col = (c>>1)*HDIM + j0 + (c&1);
    const float bv = bsum[col];
    #pragma unroll
    for (int u=0;u<4;++u) acc[c][u] = bv;
    wA[c] = wih + (size_t)col*HDIM;
    wB[c] = whh + (size_t)col*HDIM;
  }

  /* pass 1: x-dot */
  {
    const float* a = srcA + b0;
    #pragma unroll 8
    for (int k=0;k<HDIM;++k){
      const float4 av = *(const float4*)(a + (size_t)k*BATCH);
      const float xv[4] = {av.x, av.y, av.z, av.w};
      #pragma unroll
      for (int c=0;c<8;++c){
        const float w = wA[c][k];
        #pragma unroll
        for (int u=0;u<4;++u) acc[c][u] = fmaf(w, xv[u], acc[c][u]);
      }
    }
  }

  /* pass 2: masked h-dot */
  {
    const float* hbp = srcB + b0;
    #pragma unroll 8
    for (int k=0;k<HDIM;++k){
      const float4 av = *(const float4*)(hbp + (size_t)k*BATCH);
      float hv[4];
      #pragma unroll
      for (int u=0;u<4;++u) hv[u] = ((const float*)&av)[u] * ndv[u];
      #pragma unroll
      for (int c=0;c<8;++c){
        const float w = wB[c][k];
        #pragma unroll
        for (int u=0;u<4;++u) acc[c][u] = fmaf(w, hv[u], acc[c][u]);
      }
    }
  }

  /* epilogue: gates i,f,g,o -> c,h for j0,j0+1 x b0..b0+3 (float4 stores) */
  #pragma unroll
  for (int jj=0;jj<2;++jj){
    const int idx = (j0+jj)*BATCH + b0;
    const float4 co = *(const float4*)(cbuf + idx);
    float cv[4], hv2[4];
    #pragma unroll
    for (int u=0;u<4;++u){
      const float gi=acc[0+jj][u], gf=acc[2+jj][u], gg=acc[4+jj][u], go=acc[6+jj][u];
      const float cold = ((const float*)&co)[u]*ndv[u];
      const float cn = sigf_(gf)*cold + sigf_(gi)*tanhf(gg);
      const float hn = sigf_(go)*tanhf(cn);
      cv[u]=cn; hv2[u]=hn;
    }
    *(float4*)(cbuf + idx) = make_float4(cv[0],cv[1],cv[2],cv[3]);
    *(float4*)(hout + idx) = make_float4(hv2[0],hv2[1],hv2[2],hv2[3]);
  }
}

/* Skewed pipeline, 198 blocks (1 per CU): [0,66)=L0@t, [66,132)=L1@t-1,
   [132,196)=enc@t+2, 196=enc extras @t+2, 197=head+sample @t-2 */
__global__ __launch_bounds__(256) void step_kernel(
  const float* __restrict__ obs, const int* __restrict__ lastAct,
  const float* __restrict__ reward,
  const float* __restrict__ wenc,
  const float* __restrict__ wih0, const float* __restrict__ whh0,
  const float* __restrict__ wih1, const float* __restrict__ whh1,
  float* __restrict__ ws, float* __restrict__ alw,
  float* __restrict__ out, int t)
{
  const int bid = blockIdx.x;
  const int b = threadIdx.x;
  float* nd = ws + OFF_ND;
  float* xT = ws + FXT;
  float* h0 = ws + FH0;
  float* h1 = ws + FH1;
  float* c0 = ws + FC0;
  float* c1 = ws + FC1;

  if (bid < 66) {                        /* layer 0 @ t */
    if (t < 0 || t > 255) return;
    lstm_tile4(bid, b>>6, t,
               xT + (size_t)(t&3)*HB,
               h0 + (size_t)((t+1)&1)*HB,
               wih0, whh0, alw + DBS0, nd, c0,
               h0 + (size_t)(t&1)*HB, (b&63)*4);
  } else if (bid < 132) {                /* layer 1 @ t-1 */
    const int s = t - 1;
    if (s < 0 || s > 255) return;
    lstm_tile4(bid-66, b>>6, s,
               h0 + (size_t)(s&1)*HB,
               h1 + (size_t)((s+1)&1)*HB,
               wih1, whh1, alw + DBS1, nd, c1,
               h1 + (size_t)(s&1)*HB, (b&63)*4);
  } else if (bid < 197) {                /* encoder @ t+2 */
    const int te = t + 2;
    if (te < 0 || te > 255) return;
    float* xs = xT + (size_t)(te&3)*HB;
    if (bid < 196) {
      const int e = bid - 132;
      const int f0 = e*8;
      float acc[8];
      const float* wrow[8];
      #pragma unroll
      for (int c=0;c<8;++c){ acc[c]=alw[DBENC+f0+c]; wrow[c]=wenc+(size_t)(f0+c)*OBS_D; }
      __shared__ float lx[32][257];
      const int r0 = threadIdx.x>>3;
      const int kk = (threadIdx.x&7)<<2;
      for (int kc=0; kc<OBS_D; kc+=32){
        __syncthreads();
        #pragma unroll
        for (int rr=0; rr<256; rr+=32){
          const float4 v = *(const float4*)(obs + ((size_t)te*BATCH + (r0+rr))*OBS_D + kc + kk);
          lx[kk+0][r0+rr]=v.x; lx[kk+1][r0+rr]=v.y; lx[kk+2][r0+rr]=v.z; lx[kk+3][r0+rr]=v.w;
        }
        __syncthreads();
        #pragma unroll 4
        for (int k2=0;k2<32;++k2){
          const float xv = lx[k2][b];
          #pragma unroll
          for (int c=0;c<8;++c) acc[c] = fmaf(xv, wrow[c][kc+k2], acc[c]);
        }
      }
      #pragma unroll
      for (int c=0;c<8;++c) xs[(size_t)(f0+c)*BATCH + b] = fmaxf(acc[c], 0.0f);
    } else {
      const float r = reward[te*BATCH + b];
      xs[(size_t)FEATD*BATCH + b] = fminf(fmaxf(r, -1.0f), 1.0f);
      const int la = lastAct[te*BATCH + b];
      #pragma unroll
      for (int a2=0; a2<NACT; ++a2)
        xs[(size_t)(FEATD+1+a2)*BATCH + b] = (a2==la) ? 1.0f : 0.0f;
    }
  } else {                               /* head + sampling @ t-2 */
    const int s = t - 2;
    if (s < 0 || s > 255) return;
    const float* hsrc = h1 + (size_t)(s&1)*HB;
    float acc[16];
    #pragma unroll
    for (int c=0;c<16;++c) acc[c]=alw[DHB+c];
    const float* hb = hsrc + b;
    #pragma unroll 4
    for (int k=0;k<HDIM;++k){
      const float hv = hb[(size_t)k*BATCH];
      #pragma unroll
      for (int c=0;c<16;++c) acc[c] = fmaf(hv, alw[DHW + (size_t)c*HDIM + k], acc[c]);
    }
    const int row = s*BATCH + b;
    #pragma unroll
    for (int c=0;c<15;++c) out[OUT_POL + (size_t)row*NACT + c] = acc[c];
    out[OUT_BASE + row] = acc[15];
    double best = -1.0e300; int bi = 0;
    #pragma unroll
    for (int a2=0; a2<NACT; ++a2){
      const double v = (double)acc[a2] + gumbel_for((uint32_t)(row*NACT + a2));
      if (v > best){ best = v; bi = a2; }
    }
    out[OUT_ACT + row] = (float)bi;
  }
}

__global__ void finalize_kernel(const float* __restrict__ ws, float* __restrict__ out){
  int i = blockIdx.x*256 + threadIdx.x;
  if (i >= 2*HB) return;
  const int l = i / HB;
  const int r = i % HB;
  const int bq = r / HDIM;
  const int j  = r % HDIM;
  const float* hf = ws + (l==0 ? FH0 : FH1) + HB;   /* step-255 parity = 1 */
  const float* cf = ws + (l==0 ? FC0 : FC1);
  out[OUT_H + i] = hf[(size_t)j*BATCH + bq];
  out[OUT_C + i] = cf[(size_t)j*BATCH + bq];
}

extern "C" void kernel_launch(void* const* d_in, const int* in_sizes, int n_in,
                              void* d_out, int out_size, void* d_ws, size_t ws_size,
                              hipStream_t stream) {
  const float* obs     = (const float*)d_in[0];
  const int*   lastAct = (const int*)  d_in[1];
  const float* reward  = (const float*)d_in[2];
  const void*  term    =               d_in[3];
  const float* Wenc    = (const float*)d_in[4];
  const float* benc    = (const float*)d_in[5];
  const float* wih0    = (const float*)d_in[6];
  const float* whh0    = (const float*)d_in[7];
  const float* bih0    = (const float*)d_in[8];
  const float* bhh0    = (const float*)d_in[9];
  const float* wih1    = (const float*)d_in[10];
  const float* whh1    = (const float*)d_in[11];
  const float* bih1    = (const float*)d_in[12];
  const float* bhh1    = (const float*)d_in[13];
  const float* Wpol    = (const float*)d_in[14];
  const float* bpol    = (const float*)d_in[15];
  const float* Wbase   = (const float*)d_in[16];
  const float* bbase   = (const float*)d_in[17];
  float*  ws   = (float*)d_ws;
  int*    flag = (int*)(ws + OFF_FLAG);
  float*  alw  = (float*)((char*)d_ws + ALW_BYTES);
  float*  out  = (float*)d_out;

  /* zero h/c state (6*HB floats at FH0) every call */
  {
    const int nz = 6*HB;
    zero_kernel<<<(nz+255)/256, 256, 0, stream>>>(ws + FH0, nz);
  }
  detect_term_kernel<<<1, 256, 0, stream>>>(term, flag);
  nd_kernel<<<(TSTEPS*BATCH+255)/256, 256, 0, stream>>>(term, flag, ws + OFF_ND);
  prep_small_kernel<<<(DALW_N+255)/256, 256, 0, stream>>>(alw,
      bih0, bhh0, bih1, bhh1, benc, Wpol, bpol, Wbase, bbase);

  for (int t = -2; t <= 257; ++t) {
    step_kernel<<<198, 256, 0, stream>>>(
      obs, lastAct, reward,
      Wenc, wih0, whh0, wih1, whh1,
      ws, alw, out, t);
  }
  finalize_kernel<<<(2*HB+255)/256, 256, 0, stream>>>(ws, out);
}

// Round 15
// 20727.573 us; speedup vs baseline: 1.8141x; 1.8141x over previous
//
#include <hip/hip_runtime.h>
#include <stdint.h>
#include <math.h>

#define TSTEPS 256
#define BATCH  256
#define OBS_D  512
#define FEATD  512
#define NACT   15
#define HDIM   528
#define HB     (HDIM*BATCH)   /* 135168 */

/* ---- compact ws layout (same as R7, ~5.8 MB), plain [k][B] acts ---- */
#define OFF_ND    0
#define OFF_FLAG  65536
#define ALW_BYTES 262208
#define SB        91952
#define FXT       (SB)
#define FH0       (FXT + 4*HB)
#define FH1       (FH0 + 2*HB)
#define FC0       (FH1 + 2*HB)
#define FC1       (FC0 + HB)

/* ALW float offsets */
#define DBS0   0
#define DBS1   2112
#define DBENC  4224
#define DHW    4736
#define DHB    13184
#define DALW_N 13200

/* out float offsets */
#define OUT_POL   0
#define OUT_BASE  983040
#define OUT_ACT   1048576
#define OUT_H     1114112
#define OUT_C     1384448

__device__ __forceinline__ float sigf_(float x){ return 1.0f/(1.0f+expf(-x)); }

__device__ __forceinline__ uint32_t rotl32_(uint32_t x, uint32_t d){
  return (x<<d)|(x>>(32u-d));
}

/* JAX partitionable threefry 32-bit: bits = out0 ^ out1. [VERIFIED R5-R14] */
__device__ double gumbel_for(uint32_t idx){
  uint32_t x0 = 0u, x1 = idx;
  const uint32_t k0 = 0u, k1 = 1u;
  const uint32_t ks[3] = {k0, k1, 0x1BD11BDAu ^ k0 ^ k1};
  x0 += ks[0]; x1 += ks[1];
  const uint32_t R0[4] = {13u,15u,26u,6u}, R1[4] = {17u,29u,16u,24u};
  #pragma unroll
  for (int g=0; g<5; ++g){
    const uint32_t* r = (g&1) ? R1 : R0;
    #pragma unroll
    for (int j=0;j<4;++j){ x0 += x1; x1 = rotl32_(x1, r[j]); x1 ^= x0; }
    x0 += ks[(g+1)%3];
    x1 += ks[(g+2)%3] + (uint32_t)(g+1);
  }
  const uint32_t bits = x0 ^ x1;
  float u = __uint_as_float((bits>>9) | 0x3f800000u) - 1.0f;
  const float TINY = 1.17549435e-38f;
  u = u * (1.0f - TINY) + TINY;
  u = fmaxf(TINY, u);
  return -log(-log((double)u));
}

__global__ void zero_kernel(float* __restrict__ p, int n){
  int i = blockIdx.x*256 + threadIdx.x;
  if (i < n) p[i] = 0.0f;
}

__global__ void detect_term_kernel(const void* __restrict__ term, int* __restrict__ flag){
  __shared__ int s_nf, s_nb, s_ni;
  if (threadIdx.x==0){ s_nf=0; s_nb=0; s_ni=0; }
  __syncthreads();
  const uint8_t*  pb = (const uint8_t*)term;
  const uint32_t* pw = (const uint32_t*)term;
  int nf=0, nb=0, ni=0;
  for (int i=threadIdx.x; i<16384; i+=256){
    uint32_t v = pw[i];
    if (v == 0x3F800000u) nf++;
    if (v == 1u) ni++;
  }
  for (int o=threadIdx.x; o<65536; o+=256){
    if ((o&3) && pb[o]) nb++;
  }
  if (nf) atomicAdd(&s_nf, nf);
  if (nb) atomicAdd(&s_nb, nb);
  if (ni) atomicAdd(&s_ni, ni);
  __syncthreads();
  if (threadIdx.x==0){
    flag[0] = (s_nf>0) ? 2 : ((s_nb>0) ? 0 : ((s_ni>0) ? 1 : 0));
  }
}

__global__ void nd_kernel(const void* __restrict__ term, const int* __restrict__ flag,
                          float* __restrict__ nd){
  int i = blockIdx.x*256 + threadIdx.x;
  if (i >= TSTEPS*BATCH) return;
  int f = flag[0];
  bool done;
  if (f == 0)      done = ((const uint8_t*)term)[i] != 0;
  else if (f == 1) done = ((const int*)term)[i] != 0;
  else             done = ((const float*)term)[i] != 0.0f;
  nd[i] = done ? 0.0f : 1.0f;
}

__global__ void prep_small_kernel(float* __restrict__ alw,
    const float* __restrict__ bih0, const float* __restrict__ bhh0,
    const float* __restrict__ bih1, const float* __restrict__ bhh1,
    const float* __restrict__ benc,
    const float* __restrict__ Wpol, const float* __restrict__ bpol,
    const float* __restrict__ Wbase, const float* __restrict__ bbase){
  int i = blockIdx.x*256 + threadIdx.x;
  if (i >= DALW_N) return;
  if (i < 2112)            alw[DBS0 + i] = bih0[i] + bhh0[i];
  else if (i < 4224)       { int j=i-2112; alw[DBS1 + j] = bih1[j] + bhh1[j]; }
  else if (i < 4736)       { int j=i-4224; alw[DBENC + j] = benc[j]; }
  else if (i < 13184)      { int j=i-4736; int r=j/HDIM, k=j%HDIM;
                             alw[DHW + j] = (r<NACT ? Wpol[r*HDIM+k] : Wbase[k]); }
  else                     { int j=i-13184; alw[DHB + j] = (j<NACT ? bpol[j] : bbase[0]); }
}

/* One LSTM layer j-tile (8 gate cols), thread = batch row.
   Weight slab (8 rows x 1056 k = 33.8 KB) bulk-staged to LDS once (parallel
   float4 copies, one barrier), inner loop reads weights as WAVE-UNIFORM
   float4 LDS broadcasts (no bank conflicts by definition) + coalesced act
   loads. Per-acc FMA order identical to R7: bias -> x k-asc -> h k-asc. */
__device__ __forceinline__ void lstm_block(
    float* __restrict__ smem,   /* 8448 floats: [c][1056] (wih row | whh row) */
    int jt, int step, const float* __restrict__ srcA, const float* __restrict__ srcB,
    const float* __restrict__ wih, const float* __restrict__ whh,
    const float* __restrict__ bsum,
    const float* __restrict__ nd, float* __restrict__ cbuf, float* __restrict__ hout,
    int b)
{
  const int j0 = jt*2;

  /* ---- stage weights: 2112 float4s over 256 threads ---- */
  {
    for (int i = b; i < 2112; i += 256){
      const int c  = i / 264;          /* gate-col 0..7 */
      const int r4 = i - c*264;        /* float4 index within 1056 */
      const int col = (c>>1)*HDIM + j0 + (c&1);
      float4 v;
      if (r4 < 132) v = *(const float4*)(wih + (size_t)col*HDIM + r4*4);
      else          v = *(const float4*)(whh + (size_t)col*HDIM + (r4-132)*4);
      *(float4*)(smem + c*1056 + r4*4) = v;
    }
  }
  __syncthreads();

  const float ndv = nd[step*BATCH + b];
  float acc[8];
  #pragma unroll
  for (int c=0;c<8;++c) acc[c] = bsum[(c>>1)*HDIM + j0 + (c&1)];

  /* pass 1: x-dot (weights = smem[c][k], k ascending) */
  {
    const float* a = srcA + b;
    #pragma unroll 2
    for (int kq=0; kq<132; ++kq){
      float xv[4];
      #pragma unroll
      for (int u=0;u<4;++u) xv[u] = a[(size_t)(kq*4+u)*BATCH];
      #pragma unroll
      for (int c=0;c<8;++c){
        const float4 w4 = *(const float4*)(smem + c*1056 + kq*4);
        acc[c] = fmaf(w4.x, xv[0], acc[c]);
        acc[c] = fmaf(w4.y, xv[1], acc[c]);
        acc[c] = fmaf(w4.z, xv[2], acc[c]);
        acc[c] = fmaf(w4.w, xv[3], acc[c]);
      }
    }
  }

  /* pass 2: masked h-dot (weights at smem[c][528+k]) */
  {
    const float* bb = srcB + b;
    #pragma unroll 2
    for (int kq=0; kq<132; ++kq){
      float hv[4];
      #pragma unroll
      for (int u=0;u<4;++u) hv[u] = bb[(size_t)(kq*4+u)*BATCH] * ndv;
      #pragma unroll
      for (int c=0;c<8;++c){
        const float4 w4 = *(const float4*)(smem + c*1056 + 528 + kq*4);
        acc[c] = fmaf(w4.x, hv[0], acc[c]);
        acc[c] = fmaf(w4.y, hv[1], acc[c]);
        acc[c] = fmaf(w4.z, hv[2], acc[c]);
        acc[c] = fmaf(w4.w, hv[3], acc[c]);
      }
    }
  }

  #pragma unroll
  for (int jj=0;jj<2;++jj){
    const float gi=acc[0+jj], gf=acc[2+jj], gg=acc[4+jj], go=acc[6+jj];
    const int idx=(j0+jj)*BATCH+b;
    const float cold = cbuf[idx]*ndv;
    const float cn = sigf_(gf)*cold + sigf_(gi)*tanhf(gg);
    const float hn = sigf_(go)*tanhf(cn);
    cbuf[idx]=cn; hout[idx]=hn;
  }
}

/* Skewed pipeline: [0,264)=L0@t, [264,528)=L1@t-1, [528,592)=enc@t+2,
   592=enc extras @t+2, 593=head+sample @t-2 */
__global__ __launch_bounds__(256) void step_kernel(
  const float* __restrict__ obs, const int* __restrict__ lastAct,
  const float* __restrict__ reward,
  const float* __restrict__ wenc,
  const float* __restrict__ wih0, const float* __restrict__ whh0,
  const float* __restrict__ wih1, const float* __restrict__ whh1,
  float* __restrict__ ws, float* __restrict__ alw,
  float* __restrict__ out, int t)
{
  __shared__ float smem[8448];    /* LSTM slab 33.8 KB / enc tile 32.9 KB */
  const int bid = blockIdx.x;
  const int b = threadIdx.x;
  float* nd = ws + OFF_ND;
  float* xT = ws + FXT;
  float* h0 = ws + FH0;
  float* h1 = ws + FH1;
  float* c0 = ws + FC0;
  float* c1 = ws + FC1;

  if (bid < 264) {                       /* layer 0 @ t */
    if (t < 0 || t > 255) return;
    lstm_block(smem, bid, t,
               xT + (size_t)(t&3)*HB,
               h0 + (size_t)((t+1)&1)*HB,
               wih0, whh0, alw + DBS0, nd, c0,
               h0 + (size_t)(t&1)*HB, b);
  } else if (bid < 528) {                /* layer 1 @ t-1 */
    const int s = t - 1;
    if (s < 0 || s > 255) return;
    lstm_block(smem, bid-264, s,
               h0 + (size_t)(s&1)*HB,
               h1 + (size_t)((s+1)&1)*HB,
               wih1, whh1, alw + DBS1, nd, c1,
               h1 + (size_t)(s&1)*HB, b);
  } else if (bid < 593) {                /* encoder @ t+2 */
    const int te = t + 2;
    if (te < 0 || te > 255) return;
    float* xs = xT + (size_t)(te&3)*HB;
    if (bid < 592) {
      float (*lx)[257] = (float(*)[257])smem;
      const int e = bid - 528;
      const int f0 = e*8;
      float acc[8];
      const float* wrow[8];
      #pragma unroll
      for (int c=0;c<8;++c){ acc[c]=alw[DBENC+f0+c]; wrow[c]=wenc+(size_t)(f0+c)*OBS_D; }
      const int r0 = threadIdx.x>>3;
      const int kk = (threadIdx.x&7)<<2;
      for (int kc=0; kc<OBS_D; kc+=32){
        __syncthreads();
        #pragma unroll
        for (int rr=0; rr<256; rr+=32){
          const float4 v = *(const float4*)(obs + ((size_t)te*BATCH + (r0+rr))*OBS_D + kc + kk);
          lx[kk+0][r0+rr]=v.x; lx[kk+1][r0+rr]=v.y; lx[kk+2][r0+rr]=v.z; lx[kk+3][r0+rr]=v.w;
        }
        __syncthreads();
        #pragma unroll 4
        for (int k2=0;k2<32;++k2){
          const float xv = lx[k2][b];
          #pragma unroll
          for (int c=0;c<8;++c) acc[c] = fmaf(xv, wrow[c][kc+k2], acc[c]);
        }
      }
      #pragma unroll
      for (int c=0;c<8;++c) xs[(size_t)(f0+c)*BATCH + b] = fmaxf(acc[c], 0.0f);
    } else {
      const float r = reward[te*BATCH + b];
      xs[(size_t)FEATD*BATCH + b] = fminf(fmaxf(r, -1.0f), 1.0f);
      const int la = lastAct[te*BATCH + b];
      #pragma unroll
      for (int a2=0; a2<NACT; ++a2)
        xs[(size_t)(FEATD+1+a2)*BATCH + b] = (a2==la) ? 1.0f : 0.0f;
    }
  } else {                               /* head + sampling @ t-2 */
    const int s = t - 2;
    if (s < 0 || s > 255) return;
    const float* hsrc = h1 + (size_t)(s&1)*HB;
    float acc[16];
    #pragma unroll
    for (int c=0;c<16;++c) acc[c]=alw[DHB+c];
    const float* hb = hsrc + b;
    #pragma unroll 4
    for (int k=0;k<HDIM;++k){
      const float hv = hb[(size_t)k*BATCH];
      #pragma unroll
      for (int c=0;c<16;++c) acc[c] = fmaf(hv, alw[DHW + (size_t)c*HDIM + k], acc[c]);
    }
    const int row = s*BATCH + b;
    #pragma unroll
    for (int c=0;c<15;++c) out[OUT_POL + (size_t)row*NACT + c] = acc[c];
    out[OUT_BASE + row] = acc[15];
    double best = -1.0e300; int bi = 0;
    #pragma unroll
    for (int a2=0; a2<NACT; ++a2){
      const double v = (double)acc[a2] + gumbel_for((uint32_t)(row*NACT + a2));
      if (v > best){ best = v; bi = a2; }
    }
    out[OUT_ACT + row] = (float)bi;
  }
}

__global__ void finalize_kernel(const float* __restrict__ ws, float* __restrict__ out){
  int i = blockIdx.x*256 + threadIdx.x;
  if (i >= 2*HB) return;
  const int l = i / HB;
  const int r = i % HB;
  const int bq = r / HDIM;
  const int j  = r % HDIM;
  const float* hf = ws + (l==0 ? FH0 : FH1) + HB;   /* step-255 parity = 1 */
  const float* cf = ws + (l==0 ? FC0 : FC1);
  out[OUT_H + i] = hf[(size_t)j*BATCH + bq];
  out[OUT_C + i] = cf[(size_t)j*BATCH + bq];
}

extern "C" void kernel_launch(void* const* d_in, const int* in_sizes, int n_in,
                              void* d_out, int out_size, void* d_ws, size_t ws_size,
                              hipStream_t stream) {
  const float* obs     = (const float*)d_in[0];
  const int*   lastAct = (const int*)  d_in[1];
  const float* reward  = (const float*)d_in[2];
  const void*  term    =               d_in[3];
  const float* Wenc    = (const float*)d_in[4];
  const float* benc    = (const float*)d_in[5];
  const float* wih0    = (const float*)d_in[6];
  const float* whh0    = (const float*)d_in[7];
  const float* bih0    = (const float*)d_in[8];
  const float* bhh0    = (const float*)d_in[9];
  const float* wih1    = (const float*)d_in[10];
  const float* whh1    = (const float*)d_in[11];
  const float* bih1    = (const float*)d_in[12];
  const float* bhh1    = (const float*)d_in[13];
  const float* Wpol    = (const float*)d_in[14];
  const float* bpol    = (const float*)d_in[15];
  const float* Wbase   = (const float*)d_in[16];
  const float* bbase   = (const float*)d_in[17];
  float*  ws   = (float*)d_ws;
  int*    flag = (int*)(ws + OFF_FLAG);
  float*  alw  = (float*)((char*)d_ws + ALW_BYTES);
  float*  out  = (float*)d_out;

  /* zero h/c state (6*HB floats at FH0) every call */
  {
    const int nz = 6*HB;
    zero_kernel<<<(nz+255)/256, 256, 0, stream>>>(ws + FH0, nz);
  }
  detect_term_kernel<<<1, 256, 0, stream>>>(term, flag);
  nd_kernel<<<(TSTEPS*BATCH+255)/256, 256, 0, stream>>>(term, flag, ws + OFF_ND);
  prep_small_kernel<<<(DALW_N+255)/256, 256, 0, stream>>>(alw,
      bih0, bhh0, bih1, bhh1, benc, Wpol, bpol, Wbase, bbase);

  for (int t = -2; t <= 257; ++t) {
    step_kernel<<<594, 256, 0, stream>>>(
      obs, lastAct, reward,
      Wenc, wih0, whh0, wih1, whh1,
      ws, alw, out, t);
  }
  finalize_kernel<<<(2*HB+255)/256, 256, 0, stream>>>(ws, out);
}